// Round 3
// baseline (494.178 us; speedup 1.0000x reference)
//
#include <hip/hip_runtime.h>
#include <stdint.h>

#define HASH_BUCKETS 1000
#define EMB_DIM 16
#define HDIM 32
#define G4 128   // 4*HDIM
#define TSTEPS 512
#define BATCH 4096

typedef short v8s __attribute__((ext_vector_type(8)));   // 8 bf16 (4 VGPRs)
typedef float v4f __attribute__((ext_vector_type(4)));   // MFMA acc

__device__ __forceinline__ float frcp(float x) {
    float r; asm("v_rcp_f32 %0, %1" : "=v"(r) : "v"(x)); return r;
}
__device__ __forceinline__ float fexp2(float x) {
    float r; asm("v_exp_f32 %0, %1" : "=v"(r) : "v"(x)); return r;
}
// packed f32->bf16 (RNE): dst.lo16 = bf16(a), dst.hi16 = bf16(b)
__device__ __forceinline__ uint32_t cvtpk_bf16(float a, float b) {
    uint32_t r; asm("v_cvt_pk_bf16_f32 %0, %1, %2" : "=v"(r) : "v"(a), "v"(b)); return r;
}
// f32 -> bf16 (RNE), bits in low 16 (A-build only, once per launch)
__device__ __forceinline__ uint32_t bf16rne(float x) {
    uint32_t u = __float_as_uint(x);
    return (u + 0x7FFFu + ((u >> 16) & 1u)) >> 16;
}

// ---------------------------------------------------------------------------
// Kernel 1 (unchanged layout): embedding folded through input projection,
// gate exp2-scaling folded in: i/f/o rows x (-log2 e), c-row x (+2 log2 e).
// P2[bucket][h][g] = s_g * sum_e emb[bucket][e] * kernel[e][g*32 + h]
// ---------------------------------------------------------------------------
__global__ void precompute_P2_kernel(const float* __restrict__ emb,
                                     const float* __restrict__ kern,
                                     float* __restrict__ P2) {
    int idx = blockIdx.x * blockDim.x + threadIdx.x;
    if (idx >= HASH_BUCKETS * G4) return;
    int row = idx >> 7;
    int c2  = idx & 127;
    int h = c2 >> 2;
    int g = c2 & 3;
    float acc = 0.f;
#pragma unroll
    for (int e = 0; e < EMB_DIM; ++e)
        acc = fmaf(emb[row * EMB_DIM + e], kern[e * G4 + g * 32 + h], acc);
    float sg = (g == 2) ? 2.8853900817779268f : -1.4426950408889634f;
    P2[idx] = acc * sg;
}

// ---------------------------------------------------------------------------
// Kernel 2, this round: FULLY WAVE-PRIVATE recurrence. One wave = 16 batches,
// all 128 gate-rows via 8 MFMA groups with row-permutation
//   row(j, 4q+r) -> (unit 8q+j, gate r)
// so lane (col,q) computes h[8q..8q+7] of batch col == exactly its own
// B-fragment slice (k = 8q+i) for the next step. Zero h-exchange: no LDS,
// no barriers, no bank conflicts in the main loop. Evidence basis: rounds
// 1-2 proved the barrier-synced chain (~494 ns/step) is the wall; per-wave
// issue and wave count don't matter.
// ---------------------------------------------------------------------------
__global__ __launch_bounds__(64)
__attribute__((amdgpu_waves_per_eu(1, 1)))
void lstm_head_kernel(const int* __restrict__ ids,
                      const float* __restrict__ P2,   // [1000][32][4], pre-scaled
                      const float* __restrict__ R,    // rec_kernel [32][128]
                      const float* __restrict__ w1,   // [32][32]
                      const float* __restrict__ b1,   // [32]
                      const float* __restrict__ w2,   // [32]
                      const float* __restrict__ b2,   // [1]
                      float* __restrict__ out) {
    __shared__ float hfin[16][33];

    const int lane = threadIdx.x & 63;
    const int col  = lane & 15;       // batch within group (and A-row held)
    const int q    = lane >> 4;       // k-group / C-row-quad
    const int bb   = blockIdx.x * 16;

    const float PL2E   =  2.8853900817779268f;   // 2*log2(e)
    const float NL2E   = -1.4426950408889634f;
    const float N2PL2E = -5.7707801635558536f;   // -2*PL2E

    // ---- A fragments for all 8 row-groups ----
    // A_j[arow=4q'+r][k=8q+i] = sg_r * R[k][r*32 + 8q' + j], identity i->k order.
    union V8 { uint32_t u[4]; v8s v; };
    V8 Ahi[8], Alo[8];
    {
        const int arow = col;              // row of A this lane holds
        const int r  = arow & 3;
        const int qp = arow >> 2;
        const float sg = (r == 2) ? PL2E : NL2E;
#pragma unroll
        for (int j = 0; j < 8; ++j) {
            const int gcol = r * 32 + 8 * qp + j;
#pragma unroll
            for (int d = 0; d < 4; ++d) {
                uint32_t hp[2], lp[2];
#pragma unroll
                for (int e = 0; e < 2; ++e) {
                    int k = 8 * q + 2 * d + e;
                    float x = R[k * G4 + gcol] * sg;
                    uint32_t hb = bf16rne(x);
                    hp[e] = hb;
                    lp[e] = bf16rne(x - __uint_as_float(hb << 16));
                }
                Ahi[j].u[d] = hp[0] | (hp[1] << 16);
                Alo[j].u[d] = lp[0] | (lp[1] << 16);
            }
        }
    }

    // ---- state ----
    V8 Bhi, Blo;                       // h as split-bf16 B-fragment (own slice)
#pragma unroll
    for (int d = 0; d < 4; ++d) { Bhi.u[d] = 0u; Blo.u[d] = 0u; }
    float cc[8], hv[8];
#pragma unroll
    for (int j = 0; j < 8; ++j) { cc[j] = 0.f; hv[j] = 0.f; }

    // ---- xz prefetch: 32 contiguous floats per lane (units 8q..8q+7 x 4 gates)
    // ping-pong banks E (even t) / O (odd t), distance 2, zero rotate-moves.
    const int* __restrict__ idrow = ids + (size_t)(bb + col) * TSTEPS;
    const float* __restrict__ pbase = P2;   // row = id*128 + 32*q
    v4f xzE[8], xzO[8];
    {
        const float* p0 = pbase + (size_t)idrow[0] * G4 + 32 * q;
        const float* p1 = pbase + (size_t)idrow[1] * G4 + 32 * q;
#pragma unroll
        for (int j = 0; j < 8; ++j) xzE[j] = *(const v4f*)(p0 + 4 * j);
#pragma unroll
        for (int j = 0; j < 8; ++j) xzO[j] = *(const v4f*)(p1 + 4 * j);
    }
    int idE = idrow[2];
    int idO = idrow[3];

#define STEP(XZ, IDX, T)                                                        \
    {                                                                           \
        /* z_j = split-bf16 matvec + xz (3-dep MFMA chain per group,           \
           8 groups overlap; Blo only needed at chain pos 3) */                 \
        v4f z0_ = __builtin_amdgcn_mfma_f32_16x16x32_bf16(Ahi[0].v, Bhi.v, XZ[0], 0, 0, 0); \
        v4f z1_ = __builtin_amdgcn_mfma_f32_16x16x32_bf16(Ahi[1].v, Bhi.v, XZ[1], 0, 0, 0); \
        v4f z2_ = __builtin_amdgcn_mfma_f32_16x16x32_bf16(Ahi[2].v, Bhi.v, XZ[2], 0, 0, 0); \
        v4f z3_ = __builtin_amdgcn_mfma_f32_16x16x32_bf16(Ahi[3].v, Bhi.v, XZ[3], 0, 0, 0); \
        v4f z4_ = __builtin_amdgcn_mfma_f32_16x16x32_bf16(Ahi[4].v, Bhi.v, XZ[4], 0, 0, 0); \
        v4f z5_ = __builtin_amdgcn_mfma_f32_16x16x32_bf16(Ahi[5].v, Bhi.v, XZ[5], 0, 0, 0); \
        v4f z6_ = __builtin_amdgcn_mfma_f32_16x16x32_bf16(Ahi[6].v, Bhi.v, XZ[6], 0, 0, 0); \
        v4f z7_ = __builtin_amdgcn_mfma_f32_16x16x32_bf16(Ahi[7].v, Bhi.v, XZ[7], 0, 0, 0); \
        /* WAR on XZ released: prefetch t+2 into the same bank */               \
        {                                                                       \
            const float* pf_ = pbase + (size_t)(IDX) * G4 + 32 * q;             \
            _Pragma("unroll")                                                   \
            for (int j = 0; j < 8; ++j) XZ[j] = *(const v4f*)(pf_ + 4 * j);     \
        }                                                                       \
        IDX = idrow[((T) + 4 < TSTEPS) ? ((T) + 4) : (TSTEPS - 1)];             \
        z0_ = __builtin_amdgcn_mfma_f32_16x16x32_bf16(Alo[0].v, Bhi.v, z0_, 0, 0, 0); \
        z1_ = __builtin_amdgcn_mfma_f32_16x16x32_bf16(Alo[1].v, Bhi.v, z1_, 0, 0, 0); \
        z2_ = __builtin_amdgcn_mfma_f32_16x16x32_bf16(Alo[2].v, Bhi.v, z2_, 0, 0, 0); \
        z3_ = __builtin_amdgcn_mfma_f32_16x16x32_bf16(Alo[3].v, Bhi.v, z3_, 0, 0, 0); \
        z4_ = __builtin_amdgcn_mfma_f32_16x16x32_bf16(Alo[4].v, Bhi.v, z4_, 0, 0, 0); \
        z5_ = __builtin_amdgcn_mfma_f32_16x16x32_bf16(Alo[5].v, Bhi.v, z5_, 0, 0, 0); \
        z6_ = __builtin_amdgcn_mfma_f32_16x16x32_bf16(Alo[6].v, Bhi.v, z6_, 0, 0, 0); \
        z7_ = __builtin_amdgcn_mfma_f32_16x16x32_bf16(Alo[7].v, Bhi.v, z7_, 0, 0, 0); \
        z0_ = __builtin_amdgcn_mfma_f32_16x16x32_bf16(Ahi[0].v, Blo.v, z0_, 0, 0, 0); \
        z1_ = __builtin_amdgcn_mfma_f32_16x16x32_bf16(Ahi[1].v, Blo.v, z1_, 0, 0, 0); \
        z2_ = __builtin_amdgcn_mfma_f32_16x16x32_bf16(Ahi[2].v, Blo.v, z2_, 0, 0, 0); \
        z3_ = __builtin_amdgcn_mfma_f32_16x16x32_bf16(Ahi[3].v, Blo.v, z3_, 0, 0, 0); \
        z4_ = __builtin_amdgcn_mfma_f32_16x16x32_bf16(Ahi[4].v, Blo.v, z4_, 0, 0, 0); \
        z5_ = __builtin_amdgcn_mfma_f32_16x16x32_bf16(Ahi[5].v, Blo.v, z5_, 0, 0, 0); \
        z6_ = __builtin_amdgcn_mfma_f32_16x16x32_bf16(Ahi[6].v, Blo.v, z6_, 0, 0, 0); \
        z7_ = __builtin_amdgcn_mfma_f32_16x16x32_bf16(Ahi[7].v, Blo.v, z7_, 0, 0, 0); \
        v4f zz[8] = { z0_, z1_, z2_, z3_, z4_, z5_, z6_, z7_ };                 \
        _Pragma("unroll")                                                       \
        for (int j = 0; j < 8; ++j) {                                           \
            float di = 1.f + fexp2(zz[j][0]);                                   \
            float df = 1.f + fexp2(zz[j][1]);                                   \
            float dc = 1.f + fexp2(zz[j][2]);                                   \
            float dq = 1.f + fexp2(zz[j][3]);                                   \
            float Pp = di * df, Qq = dc * dq;                                   \
            float rr = frcp(Pp * Qq);                                           \
            float rP = rr * Qq, rQ = rr * Pp;                                   \
            float ig = rP * df, fg = rP * di, rc = rQ * dq, og = rQ * dc;       \
            float tz = fmaf(N2PL2E, rc, PL2E);     /* PL2E*tanh(zc) */          \
            cc[j] = fmaf(fg, cc[j], ig * tz);      /* c in PL2E domain */       \
            float tc = fmaf(-2.f, frcp(1.f + fexp2(cc[j])), 1.f);               \
            hv[j] = og * tc;                                                    \
        }                                                                       \
        /* repack own B slice (split bf16), element i <-> unit 8q+i */          \
        _Pragma("unroll")                                                       \
        for (int d = 0; d < 4; ++d) {                                           \
            uint32_t ph = cvtpk_bf16(hv[2 * d], hv[2 * d + 1]);                 \
            Bhi.u[d] = ph;                                                      \
            float lo0 = hv[2 * d]     - __uint_as_float(ph << 16);              \
            float lo1 = hv[2 * d + 1] - __uint_as_float(ph & 0xffff0000u);      \
            Blo.u[d] = cvtpk_bf16(lo0, lo1);                                    \
        }                                                                       \
    }

    for (int t = 0; t < TSTEPS; t += 2) {
        STEP(xzE, idE, t)
        STEP(xzO, idO, t + 1)
    }
#undef STEP

    // ---- MLP head (one wave: LDS transpose + shuffle reduce) ----
#pragma unroll
    for (int j = 0; j < 8; ++j)
        hfin[col][8 * q + j] = hv[j];
    __syncthreads();

    const int u = lane & 31;
#pragma unroll
    for (int it = 0; it < 8; ++it) {
        int bq = (lane >> 5) + 2 * it;
        float y = b1[u];
#pragma unroll
        for (int k = 0; k < HDIM; ++k)
            y = fmaf(hfin[bq][k], w1[k * HDIM + u], y);
        y = fmaxf(y, 0.f);
        float vv = y * w2[u];
#pragma unroll
        for (int off = 16; off >= 1; off >>= 1)
            vv += __shfl_xor(vv, off);
        if (u == 0) out[bb + bq] = vv + b2[0];
    }
}

extern "C" void kernel_launch(void* const* d_in, const int* in_sizes, int n_in,
                              void* d_out, int out_size, void* d_ws, size_t ws_size,
                              hipStream_t stream) {
    const int*   ids  = (const int*)d_in[0];
    const float* emb  = (const float*)d_in[1];
    const float* kern = (const float*)d_in[2];
    const float* rec  = (const float*)d_in[3];
    const float* w1   = (const float*)d_in[4];
    const float* b1   = (const float*)d_in[5];
    const float* w2   = (const float*)d_in[6];
    const float* b2   = (const float*)d_in[7];
    float* out = (float*)d_out;
    float* P2  = (float*)d_ws;   // 512 KB scratch

    precompute_P2_kernel<<<(HASH_BUCKETS * G4 + 255) / 256, 256, 0, stream>>>(
        emb, kern, P2);
    lstm_head_kernel<<<BATCH / 16, 64, 0, stream>>>(
        ids, P2, rec, w1, b1, w2, b2, out);
}

// Round 4
// 242.201 us; speedup vs baseline: 2.0404x; 2.0404x over previous
//
#include <hip/hip_runtime.h>
#include <stdint.h>

#define HASH_BUCKETS 1000
#define EMB_DIM 16
#define HDIM 32
#define G4 128   // 4*HDIM
#define TSTEPS 512
#define BATCH 4096

typedef short v8s __attribute__((ext_vector_type(8)));   // 8 bf16 (4 VGPRs)
typedef float v4f __attribute__((ext_vector_type(4)));   // MFMA acc

__device__ __forceinline__ float frcp(float x) {
    float r; asm("v_rcp_f32 %0, %1" : "=v"(r) : "v"(x)); return r;
}
__device__ __forceinline__ float fexp2(float x) {
    float r; asm("v_exp_f32 %0, %1" : "=v"(r) : "v"(x)); return r;
}
// packed f32->bf16 (RNE): dst.lo16 = bf16(a), dst.hi16 = bf16(b)
__device__ __forceinline__ uint32_t cvtpk_bf16(float a, float b) {
    uint32_t r; asm("v_cvt_pk_bf16_f32 %0, %1, %2" : "=v"(r) : "v"(a), "v"(b)); return r;
}
// f32 -> bf16 (RNE), bits in low 16 (A-build only, once per launch)
__device__ __forceinline__ uint32_t bf16rne(float x) {
    uint32_t u = __float_as_uint(x);
    return (u + 0x7FFFu + ((u >> 16) & 1u)) >> 16;
}

// ---------------------------------------------------------------------------
// Kernel 1 (unchanged): embedding folded through input projection, gate
// exp2-scaling folded in: i/f/o rows x (-log2 e), c-row x (+2 log2 e).
// P2[bucket][h][g] = s_g * sum_e emb[bucket][e] * kernel[e][g*32 + h]
// ---------------------------------------------------------------------------
__global__ void precompute_P2_kernel(const float* __restrict__ emb,
                                     const float* __restrict__ kern,
                                     float* __restrict__ P2) {
    int idx = blockIdx.x * blockDim.x + threadIdx.x;
    if (idx >= HASH_BUCKETS * G4) return;
    int row = idx >> 7;
    int c2  = idx & 127;
    int h = c2 >> 2;
    int g = c2 & 3;
    float acc = 0.f;
#pragma unroll
    for (int e = 0; e < EMB_DIM; ++e)
        acc = fmaf(emb[row * EMB_DIM + e], kern[e * G4 + g * 32 + h], acc);
    float sg = (g == 2) ? 2.8853900817779268f : -1.4426950408889634f;
    P2[idx] = acc * sg;
}

// ---------------------------------------------------------------------------
// Kernel 2: back to the proven 4-wave exchange structure (r1, 253us), with
// three verified-by-construction trims:
//  (a) ADJACENT unit ownership u0=8w+2q, u1=u0+1 (free A-column relabel:
//      gc0=g*32+8w+2*tt, gc1=gc0+1). Producer hi-pack = ONE dword
//      {bf16(h[2m]),bf16(h[2m+1])} at dword index m=4w+q; reader's
//      ds_read_b128 at dword 4q IS the Bhi fragment in identity k-order
//      (k = 8q + s). All 8 v_perms deleted from the read->MFMA chain.
//  (b) Conflict-free LDS by analysis (no swizzle needed): row stride 36
//      dwords; reads bank-start 4(col+q)%32 -> 8 lanes per 4-bank window =
//      exact 8-round minimum; writes 4col+q cover 0..63 -> 2-way (free).
//  (c) Unroll-2 ping-pong xz banks (E/O) + id regs: zero rotate-movs
//      (was ~26 v_mov/step); adjacent units -> contiguous 32B xz load pair
//      off one base (imm-offset folds).
// Everything else (prescaled gates, grouped reciprocal, cvt_pk split pack,
// raw lgkmcnt(0);s_barrier, distance-2 prefetch) identical to the 253us run.
// ---------------------------------------------------------------------------
__global__ __launch_bounds__(256)
__attribute__((amdgpu_waves_per_eu(1, 1)))
void lstm_head_kernel(const int* __restrict__ ids,
                      const float* __restrict__ P2,   // [1000][32][4], pre-scaled
                      const float* __restrict__ R,    // rec_kernel [32][128]
                      const float* __restrict__ w1,   // [32][32]
                      const float* __restrict__ b1,   // [32]
                      const float* __restrict__ w2,   // [32]
                      const float* __restrict__ b2,   // [1]
                      float* __restrict__ out) {
    // per col row: hi dwords [0..15] | lo dwords [16..31] | pad [4]
    __shared__ __align__(16) uint32_t hbuf[2][16][36];
    __shared__ float hfin[16][33];

    const int tid  = threadIdx.x;
    const int w    = tid >> 6;        // wave 0..3
    const int lane = tid & 63;
    const int col  = lane & 15;       // batch within group
    const int quad = lane >> 4;       // 0..3
    const int bb   = blockIdx.x * 16;
    const int u0   = 8 * w + 2 * quad;   // adjacent unit pair
    const int u1   = u0 + 1;

    const float PL2E   =  2.8853900817779268f;   // 2*log2(e)
    const float NL2E   = -1.4426950408889634f;
    const float N2PL2E = -5.7707801635558536f;   // -2*PL2E

    // ---- A fragments (identity k-order: short s=2r+e <-> k=8*quad+s) ----
    union V8 { uint32_t u[4]; v8s v; };
    V8 A0hi, A0lo, A1hi, A1lo;
    {
        int tt = col >> 2, g = col & 3;
        float sg = (g == 2) ? PL2E : NL2E;
        int gc0 = g * 32 + 8 * w + 2 * tt;   // unit 8w+2*tt (row 4*tt+g -> u0 of quad=tt)
        int gc1 = gc0 + 1;
#pragma unroll
        for (int r = 0; r < 4; ++r) {
            uint32_t h0p[2], l0p[2], h1p[2], l1p[2];
#pragma unroll
            for (int e = 0; e < 2; ++e) {
                int k = quad * 8 + 2 * r + e;
                float x0 = R[k * G4 + gc0] * sg;
                uint32_t hb0 = bf16rne(x0);
                h0p[e] = hb0;
                l0p[e] = bf16rne(x0 - __uint_as_float(hb0 << 16));
                float x1 = R[k * G4 + gc1] * sg;
                uint32_t hb1 = bf16rne(x1);
                h1p[e] = hb1;
                l1p[e] = bf16rne(x1 - __uint_as_float(hb1 << 16));
            }
            A0hi.u[r] = h0p[0] | (h0p[1] << 16);
            A0lo.u[r] = l0p[0] | (l0p[1] << 16);
            A1hi.u[r] = h1p[0] | (h1p[1] << 16);
            A1lo.u[r] = l1p[0] | (l1p[1] << 16);
        }
    }

    for (int i = tid; i < 2 * 16 * 36; i += 256)
        ((uint32_t*)hbuf)[i] = 0u;

    // ---- loop-invariant LDS addresses (no swizzle: layout is conflict-free) ----
    const uint32_t* rd[2] = { &hbuf[0][col][4 * quad],
                              &hbuf[1][col][4 * quad] };      // Bhi; Blo at +16
    uint32_t* wr[2] = { &hbuf[1][col][4 * w + quad],
                        &hbuf[0][col][4 * w + quad] };        // hi; lo at +16

    // ---- xz prefetch: contiguous 32B (units u0,u1 x 4 gates), dist-2,
    //      ping-pong E/O banks, zero moves ----
    const int* __restrict__ idrow = ids + (size_t)(bb + col) * TSTEPS;
    const float* __restrict__ baseL = P2 + 4 * u0;   // + id*G4 per step
    v4f xzE0, xzE1, xzO0, xzO1;
    {
        const float* p0 = baseL + (size_t)idrow[0] * G4;
        const float* p1 = baseL + (size_t)idrow[1] * G4;
        xzE0 = *(const v4f*)(p0);
        xzE1 = *(const v4f*)(p0 + 4);
        xzO0 = *(const v4f*)(p1);
        xzO1 = *(const v4f*)(p1 + 4);
    }
    int idE = idrow[2];
    int idO = idrow[3];

    float c0 = 0.f, c1 = 0.f, hv0 = 0.f, hv1 = 0.f;
    const v4f vzero = {0.f, 0.f, 0.f, 0.f};

    __syncthreads();

    union V8R { uint4 q; v8s v; };

#define STEP(PB, XZ0, XZ1, IDX, T)                                              \
    {                                                                           \
        /* B fragments: direct b128 reads ARE Bhi/Blo (identity k-order) */     \
        V8R Bhi, Blo;                                                           \
        Bhi.q = *(const uint4*)(rd[PB]);                                        \
        Blo.q = *(const uint4*)(rd[PB] + 16);                                   \
        v4f ma0 = __builtin_amdgcn_mfma_f32_16x16x32_bf16(A0lo.v, Bhi.v, vzero, 0, 0, 0); \
        v4f mb0 = __builtin_amdgcn_mfma_f32_16x16x32_bf16(A0hi.v, Blo.v, vzero, 0, 0, 0); \
        v4f mc0 = __builtin_amdgcn_mfma_f32_16x16x32_bf16(A0hi.v, Bhi.v, XZ0, 0, 0, 0);   \
        v4f ma1 = __builtin_amdgcn_mfma_f32_16x16x32_bf16(A1lo.v, Bhi.v, vzero, 0, 0, 0); \
        v4f mb1 = __builtin_amdgcn_mfma_f32_16x16x32_bf16(A1hi.v, Blo.v, vzero, 0, 0, 0); \
        v4f mc1 = __builtin_amdgcn_mfma_f32_16x16x32_bf16(A1hi.v, Bhi.v, XZ1, 0, 0, 0);   \
        /* xz banks consumed above -> refill same bank for t+2 (no moves) */    \
        {                                                                       \
            const float* pf_ = baseL + (size_t)(IDX) * G4;                      \
            XZ0 = *(const v4f*)(pf_);                                           \
            XZ1 = *(const v4f*)(pf_ + 4);                                       \
        }                                                                       \
        { int nt_ = (T) + 4; IDX = idrow[nt_ < TSTEPS ? nt_ : (TSTEPS - 1)]; }  \
        v4f z0 = (ma0 + mb0) + mc0;                                             \
        v4f z1 = (ma1 + mb1) + mc1;                                             \
        /* grouped-reciprocal gates (z pre-scaled: exp2 direct) */              \
        float di0 = 1.f + fexp2(z0[0]);                                         \
        float df0 = 1.f + fexp2(z0[1]);                                         \
        float dc0 = 1.f + fexp2(z0[2]);                                         \
        float dq0 = 1.f + fexp2(z0[3]);                                         \
        float di1 = 1.f + fexp2(z1[0]);                                         \
        float df1 = 1.f + fexp2(z1[1]);                                         \
        float dc1 = 1.f + fexp2(z1[2]);                                         \
        float dq1 = 1.f + fexp2(z1[3]);                                         \
        float Pp0 = di0 * df0, Qq0 = dc0 * dq0;                                 \
        float Pp1 = di1 * df1, Qq1 = dc1 * dq1;                                 \
        float rr0 = frcp(Pp0 * Qq0);                                            \
        float rr1 = frcp(Pp1 * Qq1);                                            \
        float rP0 = rr0 * Qq0, rQ0 = rr0 * Pp0;                                 \
        float rP1 = rr1 * Qq1, rQ1 = rr1 * Pp1;                                 \
        float ig0 = rP0 * df0, fg0 = rP0 * di0, rc0 = rQ0 * dq0, og0 = rQ0 * dc0; \
        float ig1 = rP1 * df1, fg1 = rP1 * di1, rc1 = rQ1 * dq1, og1 = rQ1 * dc1; \
        float tz0 = fmaf(N2PL2E, rc0, PL2E);   /* PL2E*tanh(zc) */              \
        float tz1 = fmaf(N2PL2E, rc1, PL2E);                                    \
        c0 = fmaf(fg0, c0, ig0 * tz0);         /* c in PL2E-scaled domain */    \
        c1 = fmaf(fg1, c1, ig1 * tz1);                                          \
        float tc0 = fmaf(-2.f, frcp(1.f + fexp2(c0)), 1.f);                     \
        float tc1 = fmaf(-2.f, frcp(1.f + fexp2(c1)), 1.f);                     \
        hv0 = og0 * tc0;                                                        \
        hv1 = og1 * tc1;                                                        \
        /* split-bf16 pack: one hi dword {u0,u1}, one lo dword */               \
        uint32_t ph = cvtpk_bf16(hv0, hv1);                                     \
        wr[PB][0] = ph;                                                         \
        float lo0 = hv0 - __uint_as_float(ph << 16);                            \
        float lo1 = hv1 - __uint_as_float(ph & 0xffff0000u);                    \
        wr[PB][16] = cvtpk_bf16(lo0, lo1);                                      \
        /* raw barrier: LDS drain only (xz loads live across it) */             \
        asm volatile("s_waitcnt lgkmcnt(0)\n\ts_barrier" ::: "memory");         \
    }

    for (int t = 0; t < TSTEPS; t += 2) {
        STEP(0, xzE0, xzE1, idE, t)
        STEP(1, xzO0, xzO1, idO, t + 1)
    }
#undef STEP

    // ---- MLP head ----
    hfin[col][u0] = hv0;
    hfin[col][u1] = hv1;
    __syncthreads();

    int u = tid & 31;
    for (int bq = tid >> 5; bq < 16; bq += 8) {
        float y = b1[u];
#pragma unroll
        for (int k = 0; k < HDIM; ++k)
            y = fmaf(hfin[bq][k], w1[k * HDIM + u], y);
        y = fmaxf(y, 0.f);
        float vv = y * w2[u];
#pragma unroll
        for (int off = 16; off >= 1; off >>= 1)
            vv += __shfl_xor(vv, off);
        if (u == 0) out[bb + bq] = vv + b2[0];
    }
}

extern "C" void kernel_launch(void* const* d_in, const int* in_sizes, int n_in,
                              void* d_out, int out_size, void* d_ws, size_t ws_size,
                              hipStream_t stream) {
    const int*   ids  = (const int*)d_in[0];
    const float* emb  = (const float*)d_in[1];
    const float* kern = (const float*)d_in[2];
    const float* rec  = (const float*)d_in[3];
    const float* w1   = (const float*)d_in[4];
    const float* b1   = (const float*)d_in[5];
    const float* w2   = (const float*)d_in[6];
    const float* b2   = (const float*)d_in[7];
    float* out = (float*)d_out;
    float* P2  = (float*)d_ws;   // 512 KB scratch

    precompute_P2_kernel<<<(HASH_BUCKETS * G4 + 255) / 256, 256, 0, stream>>>(
        emb, kern, P2);
    lstm_head_kernel<<<BATCH / 16, 256, 0, stream>>>(
        ids, P2, rec, w1, b1, w2, b2, out);
}